// Round 1
// baseline (1405.384 us; speedup 1.0000x reference)
//
#include <hip/hip_runtime.h>
#include <cstdint>
#include <cstddef>

#pragma clang fp contract(off)

// ---------------- configuration ----------------
// EXP_VARIANT: 2 = XLA/Eigen-Cephes exp, FMA-fused (best guess for modern XLA CPU on x86+FMA)
//              1 = same algorithm, unfused mul/add
//              3 = tanh-expansion sigmoid (placeholder)
//              4 = double-precision accurate sigmoid
#ifndef EXP_VARIANT
#define EXP_VARIANT 2
#endif

constexpr int NIMG  = 16;
constexpr int NB0   = 19200;   // 80*80*3
constexpr int NB1   = 4800;    // 40*40*3
constexpr int NB2   = 1200;    // 20*20*3
constexpr int NBOX  = 25200;
constexpr int NCLS  = 80;
constexpr int NCH   = 85;
constexpr int NBINS = 4096;
constexpr int CAP   = 4096;
constexpr int NTOP  = 1000;
constexpr int NDET  = 100;
constexpr float IMGSZ = 640.0f;
constexpr float BIN_SCALE = 4096.0f / 0.75f;

// ---------------- XLA-CPU-matching transcendentals ----------------
__device__ __forceinline__ float xla_expf(float x) {
  const float kLog2e = 1.44269504088896341f;
  const float kC1 = 0.693359375f;
  const float kC2 = -2.12194440e-4f;
  const float cp0 = 1.9875691500e-4f;
  const float cp1 = 1.3981999507e-3f;
  const float cp2 = 8.3334519073e-3f;
  const float cp3 = 4.1665795894e-2f;
  const float cp4 = 1.6666665459e-1f;
  const float cp5 = 5.0000001201e-1f;
  float xc = fminf(x, 88.3762626647950f);
  xc = fmaxf(xc, -88.3762626647949f);
#if EXP_VARIANT == 2
  float fx = floorf(fmaf(xc, kLog2e, 0.5f));
  float xr = fmaf(fx, -kC1, xc);      // xc - fx*C1, single rounding (vfnmadd on x86)
  xr = fmaf(fx, -kC2, xr);            // xr - fx*C2, single rounding
  float z = xr * xr;
  float y = fmaf(cp0, xr, cp1);
  y = fmaf(y, xr, cp2);
  y = fmaf(y, xr, cp3);
  y = fmaf(y, xr, cp4);
  y = fmaf(y, xr, cp5);
  y = fmaf(y, z, xr);
  y = y + 1.0f;
#else
  float fx = floorf(xc * kLog2e + 0.5f);
  float tmp = kC1 * fx;
  float zz = kC2 * fx;
  float xr = xc - tmp;
  xr = xr - zz;
  float z = xr * xr;
  float y = cp0 * xr + cp1;
  y = y * xr + cp2;
  y = y * xr + cp3;
  y = y * xr + cp4;
  y = y * xr + cp5;
  y = y * z + xr;
  y = y + 1.0f;
#endif
  int n = (int)fx;
  float two_n = __int_as_float((n + 127) << 23);
  float r = y * two_n;
  return fmaxf(r, xc);   // XLA's NaN/overflow trick; no-op in our range
}

__device__ __forceinline__ float ref_sigmoid(float x) {
#if EXP_VARIANT == 4
  return (float)(1.0 / (1.0 + exp(-(double)x)));
#elif EXP_VARIANT == 3
  return 0.5f + 0.5f * tanhf(0.5f * x);   // placeholder; replace with XLA tanh poly if needed
#else
  return 1.0f / (1.0f + xla_expf(-x));
#endif
}

// ---------------- geometry helper ----------------
__device__ __forceinline__ const float* locate(int img, int box,
    const float* __restrict__ p0, const float* __restrict__ p1, const float* __restrict__ p2,
    int& lvl, int& gx, int& gy, int& anc, float& stride) {
  const float* base; int r, W;
  if (box < NB0)            { lvl = 0; r = box;             W = 80; base = p0 + (size_t)img * NB0 * NCH; stride = 8.0f;  }
  else if (box < NB0 + NB1) { lvl = 1; r = box - NB0;       W = 40; base = p1 + (size_t)img * NB1 * NCH; stride = 16.0f; }
  else                      { lvl = 2; r = box - NB0 - NB1; W = 20; base = p2 + (size_t)img * NB2 * NCH; stride = 32.0f; }
  anc = r % 3;
  int cell = r / 3;
  gx = cell % W;
  gy = cell / W;
  return base + (size_t)r * NCH;
}

__device__ __forceinline__ float clip640(float v) {
  return fminf(fmaxf(v, 0.0f), IMGSZ);
}

// ---------------- kernel 1: score histogram ----------------
__global__ __launch_bounds__(256) void k_hist(const float* __restrict__ p0,
    const float* __restrict__ p1, const float* __restrict__ p2,
    unsigned int* __restrict__ ghist) {
  __shared__ unsigned int hist[NBINS];
  for (int i = threadIdx.x; i < NBINS; i += 256) hist[i] = 0u;
  __syncthreads();
  const int bpi = (NBOX + 255) / 256;   // 99
  int img = blockIdx.x / bpi;
  int box = (blockIdx.x % bpi) * 256 + threadIdx.x;
  if (box < NBOX) {
    int lvl, gx, gy, anc; float stride;
    const float* ptr = locate(img, box, p0, p1, p2, lvl, gx, gy, anc, stride);
    float obj = ref_sigmoid(ptr[4]);
    if (obj > 0.25f) {
      for (int c = 0; c < NCLS; ++c) {
        float s = obj * ref_sigmoid(ptr[5 + c]);
        if (s > 0.25f) {
          int bin = (int)((s - 0.25f) * BIN_SCALE);
          bin = min(bin, NBINS - 1);
          atomicAdd(&hist[bin], 1u);
        }
      }
    }
  }
  __syncthreads();
  for (int i = threadIdx.x; i < NBINS; i += 256) {
    unsigned int v = hist[i];
    if (v) atomicAdd(&ghist[img * NBINS + i], v);
  }
}

// ---------------- kernel 2: per-image threshold bin ----------------
__global__ void k_thresh(const unsigned int* __restrict__ ghist, int* __restrict__ tbin) {
  if (threadIdx.x != 0) return;
  int img = blockIdx.x;
  const unsigned int* h = ghist + img * NBINS;
  long long cum = 0;
  int tb = 0;
  for (int b = NBINS - 1; b >= 0; --b) {
    cum += h[b];
    tb = b;
    if (cum >= NTOP) break;
  }
  while (cum > CAP && tb < NBINS - 1) { cum -= h[tb]; ++tb; }  // pathological-tie guard
  tbin[img] = tb;
}

// ---------------- kernel 3: candidate compaction ----------------
__global__ __launch_bounds__(256) void k_compact(const float* __restrict__ p0,
    const float* __restrict__ p1, const float* __restrict__ p2,
    const int* __restrict__ tbin, unsigned long long* __restrict__ cand,
    int* __restrict__ cnt) {
  const int bpi = (NBOX + 255) / 256;
  int img = blockIdx.x / bpi;
  int box = (blockIdx.x % bpi) * 256 + threadIdx.x;
  if (box >= NBOX) return;
  int lvl, gx, gy, anc; float stride;
  const float* ptr = locate(img, box, p0, p1, p2, lvl, gx, gy, anc, stride);
  float obj = ref_sigmoid(ptr[4]);
  if (obj <= 0.25f) return;
  int tb = tbin[img];
  for (int c = 0; c < NCLS; ++c) {
    float s = obj * ref_sigmoid(ptr[5 + c]);
    if (s > 0.25f) {
      int bin = (int)((s - 0.25f) * BIN_SCALE);
      bin = min(bin, NBINS - 1);
      if (bin >= tb) {
        int pos = atomicAdd(&cnt[img], 1);
        if (pos < CAP) {
          unsigned int fi = (unsigned int)(box * NCLS + c);
          unsigned long long key =
              ((unsigned long long)__float_as_uint(s) << 32) |
              (unsigned long long)(0xFFFFFFFFu - fi);   // value desc, index asc
          cand[(size_t)img * CAP + pos] = key;
        }
      }
    }
  }
}

// ---------------- kernel 4: per-image bitonic sort, emit top-1000 ----------------
__global__ __launch_bounds__(256) void k_sort(const unsigned long long* __restrict__ cand,
    const int* __restrict__ cnt_arr, float* __restrict__ topv, int* __restrict__ topi) {
  __shared__ unsigned long long k[CAP];
  int img = blockIdx.x;
  int cnt = cnt_arr[img];
  if (cnt > CAP) cnt = CAP;
  const unsigned long long* c = cand + (size_t)img * CAP;
  for (int i = threadIdx.x; i < CAP; i += 256) k[i] = (i < cnt) ? c[i] : 0ull;
  __syncthreads();
  for (int kk = 2; kk <= CAP; kk <<= 1) {
    for (int j = kk >> 1; j > 0; j >>= 1) {
      for (int i = threadIdx.x; i < CAP; i += 256) {
        int l = i ^ j;
        if (l > i) {
          unsigned long long a = k[i], b = k[l];
          bool up = ((i & kk) == 0);            // descending overall
          bool sw = up ? (a < b) : (a > b);
          if (sw) { k[i] = b; k[l] = a; }
        }
      }
      __syncthreads();
    }
  }
  for (int i = threadIdx.x; i < NTOP; i += 256) {
    unsigned long long key = k[i];
    topv[img * NTOP + i] = __uint_as_float((unsigned int)(key >> 32));
    topi[img * NTOP + i] = (int)(0xFFFFFFFFu - (unsigned int)(key & 0xFFFFFFFFu));
  }
}

// ---------------- kernel 5: per-image NMS + output ----------------
__global__ __launch_bounds__(256) void k_nms(const float* __restrict__ p0,
    const float* __restrict__ p1, const float* __restrict__ p2,
    const float* __restrict__ anchors, const float* __restrict__ topv,
    const int* __restrict__ topi, const float* __restrict__ scalef,
    float* __restrict__ out) {
  __shared__ float obx[NTOP][4];
  __shared__ float bxs[NTOP][4];
  __shared__ float val[NTOP];
  __shared__ int   lab[NTOP];
  __shared__ int   alive[NTOP];
  __shared__ int   minj;
  const int INF = 0x7fffffff;
  int img = blockIdx.x;
  float scf = scalef[img];

  for (int t = threadIdx.x; t < NTOP; t += 256) {
    float v = topv[img * NTOP + t];
    val[t] = v;
    if (v > 0.0f) {
      int idx = topi[img * NTOP + t];
      int box = idx / NCLS;
      int l   = idx % NCLS;
      lab[t] = l;
      int lvl, gx, gy, anc; float stride;
      const float* ptr = locate(img, box, p0, p1, p2, lvl, gx, gy, anc, stride);
      float sx = ref_sigmoid(ptr[0]);
      float sy = ref_sigmoid(ptr[1]);
      float sw = ref_sigmoid(ptr[2]);
      float sh = ref_sigmoid(ptr[3]);
      float aw = anchors[(lvl * 3 + anc) * 2 + 0];
      float ah = anchors[(lvl * 3 + anc) * 2 + 1];
      float cx = (2.0f * sx - 0.5f + (float)gx) * stride;
      float cy = (2.0f * sy - 0.5f + (float)gy) * stride;
      float ww = (4.0f * (sw * sw)) * aw;
      float hh = (4.0f * (sh * sh)) * ah;
      float b0 = clip640(cx - ww * 0.5f);
      float b1 = clip640(cy - hh * 0.5f);
      float b2 = clip640(cx + ww * 0.5f);
      float b3 = clip640(cy + hh * 0.5f);
      bxs[t][0] = b0; bxs[t][1] = b1; bxs[t][2] = b2; bxs[t][3] = b3;
      float off = (float)l * 4096.0f;
      obx[t][0] = b0 + off; obx[t][1] = b1 + off;
      obx[t][2] = b2 + off; obx[t][3] = b3 + off;
      alive[t] = 1;
    } else {
      lab[t] = -1; alive[t] = 0;
      bxs[t][0] = bxs[t][1] = bxs[t][2] = bxs[t][3] = 0.0f;
      obx[t][0] = obx[t][1] = obx[t][2] = obx[t][3] = 0.0f;
    }
  }
  __syncthreads();

  for (int i = 0; i < NDET; ++i) {
    if (threadIdx.x == 0) minj = INF;
    __syncthreads();
    int local = INF;
    for (int t = threadIdx.x; t < NTOP; t += 256)
      if (alive[t] && t < local) local = t;
    if (local != INF) atomicMin(&minj, local);
    __syncthreads();
    int j = minj;
    float* orow = out + ((size_t)img * NDET + i) * 6;
    if (j == INF) {
      if (threadIdx.x == 0) {
        orow[0] = 0.0f; orow[1] = 0.0f; orow[2] = 0.0f;
        orow[3] = 0.0f; orow[4] = 0.0f; orow[5] = -1.0f;
      }
      __syncthreads();
      continue;
    }
    if (threadIdx.x == 0) {
      orow[0] = bxs[j][0] / scf; orow[1] = bxs[j][1] / scf;
      orow[2] = bxs[j][2] / scf; orow[3] = bxs[j][3] / scf;
      orow[4] = val[j];
      orow[5] = (float)lab[j];
    }
    float a0 = obx[j][0], a1c = obx[j][1], a2c = obx[j][2], a3c = obx[j][3];
    float areaA = (a2c - a0) * (a3c - a1c);
    int lj = lab[j];
    for (int t = threadIdx.x; t < NTOP; t += 256) {
      if (!alive[t] || lab[t] != lj) continue;   // cross-class IoU is exactly 0 in ref
      float ltx = fmaxf(a0, obx[t][0]);
      float lty = fmaxf(a1c, obx[t][1]);
      float rbx = fminf(a2c, obx[t][2]);
      float rby = fminf(a3c, obx[t][3]);
      float wx = fmaxf(rbx - ltx, 0.0f);
      float wy = fmaxf(rby - lty, 0.0f);
      float inter = wx * wy;
      float a2 = (obx[t][2] - obx[t][0]) * (obx[t][3] - obx[t][1]);
      float denom = areaA + a2 - inter + 1e-7f;  // ((a1+a2)-inter)+1e-7, contract off
      float iou = inter / denom;
      if (iou > 0.45f) alive[t] = 0;             // includes t==j unless degenerate (ref quirk)
    }
    __syncthreads();
  }
}

// ---------------- launcher ----------------
extern "C" void kernel_launch(void* const* d_in, const int* in_sizes, int n_in,
                              void* d_out, int out_size, void* d_ws, size_t ws_size,
                              hipStream_t stream) {
  const float* p0 = (const float*)d_in[0];
  const float* p1 = (const float*)d_in[1];
  const float* p2 = (const float*)d_in[2];
  const float* anchors = (const float*)d_in[3];
  const float* scalef  = (const float*)d_in[4];
  float* out = (float*)d_out;

  char* w = (char*)d_ws;
  // layout: hist | cnt | tbin | cand | topv | topi   (~0.9 MB total)
  unsigned int* ghist = (unsigned int*)(w);                          // 16*4096*4 = 262144
  int* cnt  = (int*)(w + 262144);                                    // 64
  int* tbin = (int*)(w + 262208);                                    // 64
  unsigned long long* cand = (unsigned long long*)(w + 262272);      // 16*4096*8 = 524288
  float* topv = (float*)(w + 786560);                                // 16*1000*4 = 64000
  int*   topi = (int*)(w + 850560);                                  // 64000

  hipMemsetAsync(ghist, 0, 262144 + 64, stream);   // hist + cnt

  const int bpi = (NBOX + 255) / 256;              // 99
  k_hist<<<dim3(NIMG * bpi), dim3(256), 0, stream>>>(p0, p1, p2, ghist);
  k_thresh<<<dim3(NIMG), dim3(64), 0, stream>>>(ghist, tbin);
  k_compact<<<dim3(NIMG * bpi), dim3(256), 0, stream>>>(p0, p1, p2, tbin, cand, cnt);
  k_sort<<<dim3(NIMG), dim3(256), 0, stream>>>(cand, cnt, topv, topi);
  k_nms<<<dim3(NIMG), dim3(256), 0, stream>>>(p0, p1, p2, anchors, topv, topi, scalef, out);
}